// Round 3
// baseline (532.139 us; speedup 1.0000x reference)
//
#include <hip/hip_runtime.h>
#include <hip/hip_bf16.h>
#include <stdint.h>

#define NGn 100000
#define NDn 100000
#define NEn 400000
#define ELn 200000

typedef __bf16 bf16x8 __attribute__((ext_vector_type(8)));
typedef float  f32x4  __attribute__((ext_vector_type(4)));

__device__ __forceinline__ bf16x8 cvt8(const float* __restrict__ f) {
    f32x4 a = *(const f32x4*)f;
    f32x4 b = *(const f32x4*)(f + 4);
    bf16x8 r;
    r[0] = (__bf16)a[0]; r[1] = (__bf16)a[1]; r[2] = (__bf16)a[2]; r[3] = (__bf16)a[3];
    r[4] = (__bf16)b[0]; r[5] = (__bf16)b[1]; r[6] = (__bf16)b[2]; r[7] = (__bf16)b[3];
    return r;
}

// ---------------------------------------------------------------------------
// Mask scatter: mark nodes that appear as DST of at least one edge.
// ---------------------------------------------------------------------------
__global__ void scatter_mask(const int* __restrict__ g2d_dst,
                             const int* __restrict__ d2g_dst,
                             uint8_t* __restrict__ mask_d,
                             uint8_t* __restrict__ mask_g, int n) {
    int i = blockIdx.x * blockDim.x + threadIdx.x;
    if (i < n) {
        mask_d[g2d_dst[i]] = 1;
        mask_g[d2g_dst[i]] = 1;
    }
}

// ---------------------------------------------------------------------------
// Z[r,:] = relu(X[r,:] @ W + b) * mask[r].  X,W,b f32; Z stored f32 (output)
// and optionally bf16 (workspace mirror for the MLP gather).
// Grid-stride over 64-row tiles; W staged bf16-transposed in LDS once/block.
// ---------------------------------------------------------------------------
__global__ __launch_bounds__(256) void node_gemm(
    const float* __restrict__ X, const float* __restrict__ W,
    const float* __restrict__ bias, const uint8_t* __restrict__ mask,
    float* __restrict__ Zf, __bf16* __restrict__ Zb, int Nrows)
{
    __shared__ __bf16 Wt[128 * 136];   // Wt[c][k], stride 136 halves
    const int tid = threadIdx.x;
    for (int idx = tid; idx < 128 * 128; idx += 256) {
        int k = idx >> 7, c = idx & 127;
        Wt[c * 136 + k] = (__bf16)W[idx];
    }
    __syncthreads();

    const int wave = tid >> 6;
    const int lane = tid & 63;
    const int m = lane & 15;      // A-row within tile / D col
    const int q = lane >> 4;      // quad

    float bcol[8];
#pragma unroll
    for (int nt = 0; nt < 8; ++nt) bcol[nt] = bias[nt * 16 + m];

    const int ntiles = (Nrows + 63) >> 6;
    for (int t = blockIdx.x; t < ntiles; t += gridDim.x) {
        const int base = t * 64;
        const int row_a = base + wave * 16 + m;
        const int rowa_c = row_a < Nrows ? row_a : (Nrows - 1);

        f32x4 acc[8];
#pragma unroll
        for (int nt = 0; nt < 8; ++nt) acc[nt] = f32x4{0.f, 0.f, 0.f, 0.f};

#pragma unroll
        for (int kk = 0; kk < 4; ++kk) {
            bf16x8 a = cvt8(X + (size_t)rowa_c * 128 + kk * 32 + q * 8);
#pragma unroll
            for (int nt = 0; nt < 8; ++nt) {
                bf16x8 b = *(const bf16x8*)(&Wt[(nt * 16 + m) * 136 + kk * 32 + q * 8]);
                acc[nt] = __builtin_amdgcn_mfma_f32_16x16x32_bf16(a, b, acc[nt], 0, 0, 0);
            }
        }

#pragma unroll
        for (int reg = 0; reg < 4; ++reg) {
            int r = base + wave * 16 + q * 4 + reg;
            if (r < Nrows) {
                float mk = mask[r] ? 1.f : 0.f;
#pragma unroll
                for (int nt = 0; nt < 8; ++nt) {
                    float v = acc[nt][reg] + bcol[nt];
                    v = (v > 0.f ? v : 0.f) * mk;
                    Zf[(size_t)r * 128 + nt * 16 + m] = v;
                    if (Zb) Zb[(size_t)r * 128 + nt * 16 + m] = (__bf16)v;
                }
            }
        }
    }
}

// ---------------------------------------------------------------------------
// MLP over label edges: z = [zg[row] ; zd[col]] (256), h = relu(z@W1+b1),
// pred = h@W2 + b2 (f32 out). Gathers from bf16 mirror if usebf, else from
// the f32 z in d_out. W1 staged bf16 XOR-swizzled in LDS.
// ---------------------------------------------------------------------------
__global__ __launch_bounds__(256) void mlp_kernel(
    const __bf16* __restrict__ zgb, const __bf16* __restrict__ zdb,
    const float* __restrict__ zgf, const float* __restrict__ zdf,
    int usebf, const int* __restrict__ eli,
    const float* __restrict__ W1, const float* __restrict__ b1,
    const float* __restrict__ W2, const float* __restrict__ b2,
    float* __restrict__ pred)
{
    __shared__ __bf16 Wt[128 * 256];   // Wt[n][k'], k' XOR-swizzled per 8-half chunk
    const int tid = threadIdx.x;
    for (int idx = tid; idx < 256 * 128; idx += 256) {
        int k = idx >> 7, c = idx & 127;
        int kc = k >> 3, kl = k & 7;
        Wt[c * 256 + ((kc ^ (c & 7)) * 8 + kl)] = (__bf16)W1[idx];
    }
    __syncthreads();

    const int wave = tid >> 6;
    const int lane = tid & 63;
    const int m = lane & 15;
    const int q = lane >> 4;

    float b1c[8], w2c[8];
#pragma unroll
    for (int nt = 0; nt < 8; ++nt) {
        b1c[nt] = b1[nt * 16 + m];
        w2c[nt] = W2[nt * 16 + m];
    }
    const float bb = b2[0];

    const int ngroups = ELn / 64;
    for (int g = blockIdx.x; g < ngroups; g += gridDim.x) {
        const int e = g * 64 + wave * 16 + m;
        const int grow = eli[e];
        const int dcol = eli[ELn + e];

        f32x4 acc[8];
#pragma unroll
        for (int nt = 0; nt < 8; ++nt) acc[nt] = f32x4{0.f, 0.f, 0.f, 0.f};

#pragma unroll
        for (int kk = 0; kk < 8; ++kk) {
            bf16x8 a;
            if (usebf) {
                const __bf16* src = (kk < 4) ? (zgb + (size_t)grow * 128 + kk * 32)
                                             : (zdb + (size_t)dcol * 128 + (kk - 4) * 32);
                a = *(const bf16x8*)(src + q * 8);
            } else {
                const float* src = (kk < 4) ? (zgf + (size_t)grow * 128 + kk * 32)
                                            : (zdf + (size_t)dcol * 128 + (kk - 4) * 32);
                a = cvt8(src + q * 8);
            }
            const int kcr = kk * 4 + q;
#pragma unroll
            for (int nt = 0; nt < 8; ++nt) {
                int n = nt * 16 + m;
                bf16x8 b = *(const bf16x8*)(&Wt[n * 256 + ((kcr ^ (n & 7)) * 8)]);
                acc[nt] = __builtin_amdgcn_mfma_f32_16x16x32_bf16(a, b, acc[nt], 0, 0, 0);
            }
        }

        float pb[4];
#pragma unroll
        for (int reg = 0; reg < 4; ++reg) {
            float s = 0.f;
#pragma unroll
            for (int nt = 0; nt < 8; ++nt) {
                float h = acc[nt][reg] + b1c[nt];
                h = h > 0.f ? h : 0.f;
                s += h * w2c[nt];
            }
            pb[reg] = s;
        }
#pragma unroll
        for (int off = 1; off < 16; off <<= 1) {
#pragma unroll
            for (int reg = 0; reg < 4; ++reg)
                pb[reg] += __shfl_xor(pb[reg], off, 64);
        }
        if (m == 0) {
#pragma unroll
            for (int reg = 0; reg < 4; ++reg) {
                int er = g * 64 + wave * 16 + q * 4 + reg;
                pred[er] = pb[reg] + bb;
            }
        }
    }
}

// ---------------------------------------------------------------------------
extern "C" void kernel_launch(void* const* d_in, const int* in_sizes, int n_in,
                              void* d_out, int out_size, void* d_ws, size_t ws_size,
                              hipStream_t stream) {
    const float* x_gene    = (const float*)d_in[0];
    const float* x_disease = (const float*)d_in[1];
    const int*   ei_g2d    = (const int*)d_in[2];
    const int*   ei_d2g    = (const int*)d_in[3];
    const int*   eli       = (const int*)d_in[6];
    const float* Wn_gene   = (const float*)d_in[7];
    const float* bn_gene   = (const float*)d_in[8];
    const float* Wn_dis    = (const float*)d_in[9];
    const float* bn_dis    = (const float*)d_in[10];
    const float* W1        = (const float*)d_in[17];
    const float* b1        = (const float*)d_in[18];
    const float* W2        = (const float*)d_in[19];
    const float* b2        = (const float*)d_in[20];

    float* out   = (float*)d_out;
    float* predp = out;                                   // [200000]
    float* zgf   = out + ELn;                             // [100000*128]
    float* zdf   = zgf + (size_t)NGn * 128;               // [100000*128]

    uint8_t* mask_d = (uint8_t*)d_ws;                     // [ND]
    uint8_t* mask_g = mask_d + NDn;                       // [NG]

    const size_t zelems = (size_t)NGn * 128;              // 12.8M
    const size_t mirror_off = 200704;                     // masks, 256-aligned
    const bool   mirror = ws_size >= mirror_off + 2 * zelems * sizeof(__bf16);
    __bf16* zgb = mirror ? (__bf16*)((char*)d_ws + mirror_off) : nullptr;
    __bf16* zdb = mirror ? zgb + zelems : nullptr;

    hipMemsetAsync(d_ws, 0, NGn + NDn, stream);
    scatter_mask<<<(NEn + 255) / 256, 256, 0, stream>>>(
        ei_g2d + NEn, ei_d2g + NEn, mask_d, mask_g, NEn);

    node_gemm<<<1024, 256, 0, stream>>>(x_gene, Wn_gene, bn_gene, mask_g, zgf, zgb, NGn);
    node_gemm<<<1024, 256, 0, stream>>>(x_disease, Wn_dis, bn_dis, mask_d, zdf, zdb, NDn);

    mlp_kernel<<<512, 256, 0, stream>>>(zgb, zdb, zgf, zdf, mirror ? 1 : 0,
                                        eli, W1, b1, W2, b2, predp);
}